// Round 9
// baseline (1702.064 us; speedup 1.0000x reference)
//
#include <hip/hip_runtime.h>
#include <math.h>

#define T_   2048
#define DIN  512
#define H_   384
#define H4_  1536
#define BT_  16384

typedef _Float16 half_t;
typedef _Float16 f16x8 __attribute__((ext_vector_type(8)));
typedef _Float16 f16x4 __attribute__((ext_vector_type(4)));
typedef float f32x4 __attribute__((ext_vector_type(4)));

#define LO_SCALE 2048.0f
#define LO_INV   4.8828125e-4f

// async global->LDS DMA, 16 B per lane (1 KB per wave-instruction).
__device__ __forceinline__ void gload_lds(const half_t* g, half_t* l) {
    __builtin_amdgcn_global_load_lds(
        (const __attribute__((address_space(1))) unsigned int*)(const void*)g,
        (__attribute__((address_space(3))) unsigned int*)(void*)l, 16, 0, 0);
}

__device__ __forceinline__ void split2(float v, half_t* hi, half_t* lo) {
    half_t h = (half_t)v;
    *hi = h;
    *lo = (half_t)((v - (float)h) * LO_SCALE);
}

// ---------------------------------------------------------------------------
// fp32 -> (hi, lo*2048) fp16 split, 4 elems/thread (G13 vectorized)
// ---------------------------------------------------------------------------
__global__ void k_split4(const float* __restrict__ in, half_t* __restrict__ hi,
                         half_t* __restrict__ lo, long n4) {
    long i = (long)blockIdx.x * 256 + threadIdx.x;
    if (i >= n4) return;
    float4 v = ((const float4*)in)[i];
    f16x4 vh, vl;
    float a[4] = {v.x, v.y, v.z, v.w};
#pragma unroll
    for (int j = 0; j < 4; ++j) {
        half_t h = (half_t)a[j];
        vh[j] = h;
        vl[j] = (half_t)((a[j] - (float)h) * LO_SCALE);
    }
    ((f16x4*)hi)[i] = vh;
    ((f16x4*)lo)[i] = vl;
}

// ---------------------------------------------------------------------------
// t-padded split of x: xpad[b][u][ii] = x[b][u-3][ii] for u in [3,2051),
// zeros at pads (u<3 or u>=2051); u in [0,2054). With the [tap*512+ii]
// K-ordering, im2row row (b,t) is then the CONTIGUOUS 3584-half slice at
// (b*2054+t)*512 -- exact fit: 2047*512+3583 = 2054*512-1. This turns the
// encoder conv into a plain row-major GEMM (no bounds check -> DMA-stageable).
// ---------------------------------------------------------------------------
__global__ void k_split_pad(const float* __restrict__ in, half_t* __restrict__ hi,
                            half_t* __restrict__ lo) {
    long i = (long)blockIdx.x * 256 + threadIdx.x;   // 4-elem granule
    if (i >= 2103296L) return;                        // 8*2054*128
    int ii4 = (int)(i & 127);
    long rest = i >> 7;
    int u = (int)(rest % 2054);
    int b = (int)(rest / 2054);
    f16x4 vh = (f16x4)(half_t)0.f, vl = (f16x4)(half_t)0.f;
    if (u >= 3 && u < 2051) {
        float4 v = ((const float4*)in)[((long)b * 2048 + (u - 3)) * 128 + ii4];
        float a[4] = {v.x, v.y, v.z, v.w};
#pragma unroll
        for (int j = 0; j < 4; ++j) {
            half_t h = (half_t)a[j];
            vh[j] = h;
            vl[j] = (half_t)((a[j] - (float)h) * LO_SCALE);
        }
    }
    ((f16x4*)hi)[i] = vh;
    ((f16x4*)lo)[i] = vl;
}

// enc_w [H][DIN][7] -> [H][tap*512+i] hi/lo
__global__ void k_split_encw(const float* __restrict__ in, half_t* __restrict__ hi,
                             half_t* __restrict__ lo) {
    int idx = blockIdx.x * 256 + threadIdx.x;
    if (idx >= H_ * 3584) return;
    int n = idx / 3584;
    int r = idx % 3584;
    int tap = r >> 9, i = r & 511;
    split2(in[n * 3584 + i * 7 + tap], hi + idx, lo + idx);
}

// ---------------------------------------------------------------------------
// Row-wise LayerNorm over H=384 (fp32 in/out, in-place safe), one wave per row
// ---------------------------------------------------------------------------
__global__ void k_ln(const float* __restrict__ in, float* __restrict__ out,
                     const float* __restrict__ g, const float* __restrict__ b) {
    int row = blockIdx.x;
    int lane = threadIdx.x;
    const float* ir = in + (long)row * H_;
    float v[6];
    float s = 0.f;
#pragma unroll
    for (int j = 0; j < 6; ++j) { v[j] = ir[lane + (j << 6)]; s += v[j]; }
#pragma unroll
    for (int o = 32; o > 0; o >>= 1) s += __shfl_down(s, o, 64);
    s = __shfl(s, 0, 64);
    float mean = s * (1.f / 384.f);
    float q = 0.f;
#pragma unroll
    for (int j = 0; j < 6; ++j) { float d = v[j] - mean; q += d * d; }
#pragma unroll
    for (int o = 32; o > 0; o >>= 1) q += __shfl_down(q, o, 64);
    q = __shfl(q, 0, 64);
    float rstd = rsqrtf(q * (1.f / 384.f) + 1e-5f);
    float* orow = out + (long)row * H_;
#pragma unroll
    for (int j = 0; j < 6; ++j) {
        int c = lane + (j << 6);
        orow[c] = (v[j] - mean) * rstd * g[c] + b[c];
    }
}

// ---------------------------------------------------------------------------
// Fused depthwise conv (k=7, pad=3) + LayerNorm; emits fp16 hi/lo for GEMM1.
// float2-vectorized h loads (G13).
// ---------------------------------------------------------------------------
__global__ __launch_bounds__(256) void k_dwconv_ln(
    const float* __restrict__ h, half_t* __restrict__ oh,
    half_t* __restrict__ ol,
    const float* __restrict__ w, const float* __restrict__ wb,
    const float* __restrict__ g, const float* __restrict__ gb) {
    int row = (blockIdx.x << 2) + (threadIdx.x >> 6);
    int b = row >> 11;
    int t = row & 2047;
    int lane = threadIdx.x & 63;
    const float* hb = h + ((long)b * T_) * H_;
    float vx[3], vy[3];
    float s = 0.f;
#pragma unroll
    for (int j = 0; j < 3; ++j) {
        int c = (lane << 1) + (j << 7);
        float ax = wb[c], ay = wb[c + 1];
        const float* wcx = w + c * 7;
        const float* wcy = wcx + 7;
#pragma unroll
        for (int k = 0; k < 7; ++k) {
            int tt = t + k - 3;
            if ((unsigned)tt < (unsigned)T_) {
                float2 hv = *(const float2*)&hb[(long)tt * H_ + c];
                ax = fmaf(hv.x, wcx[k], ax);
                ay = fmaf(hv.y, wcy[k], ay);
            }
        }
        vx[j] = ax; vy[j] = ay;
        s += ax + ay;
    }
#pragma unroll
    for (int o = 32; o > 0; o >>= 1) s += __shfl_down(s, o, 64);
    s = __shfl(s, 0, 64);
    float mean = s * (1.f / 384.f);
    float q = 0.f;
#pragma unroll
    for (int j = 0; j < 3; ++j) {
        float dx = vx[j] - mean, dy = vy[j] - mean;
        q += dx * dx + dy * dy;
    }
#pragma unroll
    for (int o = 32; o > 0; o >>= 1) q += __shfl_down(q, o, 64);
    q = __shfl(q, 0, 64);
    float rstd = rsqrtf(q * (1.f / 384.f) + 1e-5f);
    long ro = (long)row * H_;
#pragma unroll
    for (int j = 0; j < 3; ++j) {
        int c = (lane << 1) + (j << 7);
        float valx = (vx[j] - mean) * rstd * g[c] + gb[c];
        float valy = (vy[j] - mean) * rstd * g[c + 1] + gb[c + 1];
        split2(valx, oh + ro + c, ol + ro + c);
        split2(valy, oh + ro + c + 1, ol + ro + c + 1);
    }
}

// ---------------------------------------------------------------------------
// MFMA fp16x3 GEMM "g192p": BM=128 x BN=192, BK=32, 512 threads = 8 waves
// (2m x 4n), wave tile 64x48. Ring-3 LDS (120 KB) + counted vmcnt(5) +
// 3-phase fine interleave (r8-verified: first structural gain, m196/m218
// mechanism). DMA staging with pre-swizzled per-lane source (m173).
//   P1: ds_read Ah(4)+Bl(3), stage 2/5 DMA(t+2) -> bar -> 12 MFMA (Ah*Bl)
//   P2: ds_read Al(4)+Bh(3), stage 3/5 DMA      -> bar -> 12 MFMA (Al*Bh)
//   P3: (frags live)                                   -> 12 MFMA (Ah*Bh)
// MODE 0: A = padded im2row x (row stride 512, K=3584), +bias, fp32 out.
//         Grid 128m x 2n = 256 = 1 exact round. (r9: replaces k_mgemm64,
//         which sat at 34% MfmaUtil on the old 2-phase structure.)
// MODE 1: +bias, exact GELU, fp16 hi/lo out (smem round-trip, stride 200)
// MODE 2: +bias, +res, fp32 out
// Buf layout (halves, stride 20480): Ahi@0 Alo@4096 Bhi@8192 Blo@14336.
// ---------------------------------------------------------------------------
template <int MODE, int NT>
__global__ __launch_bounds__(512, 2) void k_g192p(
    const half_t* __restrict__ Ah, const half_t* __restrict__ Al,
    const half_t* __restrict__ Bh, const half_t* __restrict__ Bl,
    const float* __restrict__ bias, const float* __restrict__ res,
    float* __restrict__ Cf, half_t* __restrict__ Ch, half_t* __restrict__ Cl,
    int N, int K) {
    __shared__ __align__(16) half_t smem[61440];
    const int tid = threadIdx.x;
    const int lane = tid & 63, wid = tid >> 6;
    const int wm = (wid & 1) << 6;          // {0, 64}
    const int wn = ((wid >> 1) & 3) * 48;   // {0, 48, 96, 144}
    const int quad = lane >> 4, l16 = lane & 15;

    constexpr int NWG = 128 * NT;
    constexpr int CHUNK = NWG / 8;
    const int lin = blockIdx.x;
    const int tile = (lin & 7) * CHUNK + (lin >> 3);
    const int m0 = (tile / NT) << 7;
    const int n0 = (tile % NT) * 192;

    // A row addressing: MODE 0 reads the padded im2row (stride 512,
    // base row b*2054 + t0); others are plain row-major stride K.
    long abase;
    int astr;
    if (MODE == 0) {
        abase = (long)(m0 >> 11) * 2054 + (m0 & 2047);
        astr = 512;
    } else {
        abase = m0;
        astr = K;
    }

    // per-lane DMA source swizzle (m173, r6-r8-verified)
    const int lr = lane >> 2;
    const int lg = (lane & 3) ^ ((lane >> 3) & 3);
    const half_t* gsrc[5];
    int ldo[5];
#pragma unroll
    for (int j = 0; j < 5; ++j) {
        int q = wid * 5 + j;
        if (q < 8) {
            gsrc[j] = Ah + (abase + q * 16 + lr) * (long)astr + lg * 8;
            ldo[j] = q * 512;
        } else if (q < 16) {
            gsrc[j] = Al + (abase + (q - 8) * 16 + lr) * (long)astr + lg * 8;
            ldo[j] = 4096 + (q - 8) * 512;
        } else if (q < 28) {
            gsrc[j] = Bh + ((long)(n0 + (q - 16) * 16 + lr)) * K + lg * 8;
            ldo[j] = 8192 + (q - 16) * 512;
        } else {
            gsrc[j] = Bl + ((long)(n0 + (q - 28) * 16 + lr)) * K + lg * 8;
            ldo[j] = 14336 + (q - 28) * 512;
        }
    }

#define STAGE3(bufb, k0_) do {                                              \
    int k0v = (k0_);                                                        \
    _Pragma("unroll")                                                       \
    for (int j = 0; j < 5; ++j)                                             \
        gload_lds(gsrc[j] + k0v, &smem[(bufb) + ldo[j]]);                   \
} while (0)

    f32x4 acc1[4][3] = {};
    f32x4 acc2[4][3] = {};
    const int sw = ((quad ^ (l16 >> 1)) & 3) << 3;

    const int nIter = K >> 5;   // 112 (enc) / 12 (G1) / 48 (G2); >= 3
    STAGE3(0, 0);
    STAGE3(20480, 32);
    int b0 = 0, b1 = 20480, b2 = 40960;
    for (int it = 0; it < nIter; ++it) {
        if (it + 1 < nIter)
            asm volatile("s_waitcnt vmcnt(5)" ::: "memory");
        else
            asm volatile("s_waitcnt vmcnt(0)" ::: "memory");
        __builtin_amdgcn_s_barrier();
        __builtin_amdgcn_sched_barrier(0);

        const int ab = b0 + (wm + l16) * 32 + sw;
        const int bb = b0 + 8192 + (wn + l16) * 32 + sw;
        const int k2 = (it + 2) << 5;
        const bool st = (it + 2 < nIter);
        f16x8 fah[4], fal[4], fgh[3], fgl[3];

        // ---- P1: Ah + Bl reads, 2/5 staging, 12 MFMA (Ah*Bl)
#pragma unroll
        for (int f = 0; f < 4; ++f)
            fah[f] = *(const f16x8*)&smem[ab + f * 512];
#pragma unroll
        for (int g = 0; g < 3; ++g)
            fgl[g] = *(const f16x8*)&smem[bb + 6144 + g * 512];
        if (st) {
            gload_lds(gsrc[0] + k2, &smem[b2 + ldo[0]]);
            gload_lds(gsrc[1] + k2, &smem[b2 + ldo[1]]);
        }
        __builtin_amdgcn_s_barrier();
        __builtin_amdgcn_sched_barrier(0);
        __builtin_amdgcn_s_setprio(1);
#pragma unroll
        for (int f = 0; f < 4; ++f)
#pragma unroll
            for (int g = 0; g < 3; ++g)
                acc2[f][g] = __builtin_amdgcn_mfma_f32_16x16x32_f16(fah[f], fgl[g], acc2[f][g], 0, 0, 0);
        __builtin_amdgcn_s_setprio(0);
        __builtin_amdgcn_sched_barrier(0);
        __builtin_amdgcn_s_barrier();

        // ---- P2: Al + Bh reads, 3/5 staging, 12 MFMA (Al*Bh)
#pragma unroll
        for (int f = 0; f < 4; ++f)
            fal[f] = *(const f16x8*)&smem[ab + 4096 + f * 512];
#pragma unroll
        for (int g = 0; g < 3; ++g)
            fgh[g] = *(const f16x8*)&smem[bb + g * 512];
        if (st) {
            gload_lds(gsrc[2] + k2, &smem[b2 + ldo[2]]);
            gload_lds(gsrc[3] + k2, &smem[b2 + ldo[3]]);
            gload_lds(gsrc[4] + k2, &smem[b2 + ldo[4]]);
        }
        __builtin_amdgcn_s_barrier();
        __builtin_amdgcn_sched_barrier(0);
        __builtin_amdgcn_s_setprio(1);
#pragma unroll
        for (int f = 0; f < 4; ++f)
#pragma unroll
            for (int g = 0; g < 3; ++g)
                acc2[f][g] = __builtin_amdgcn_mfma_f32_16x16x32_f16(fal[f], fgh[g], acc2[f][g], 0, 0, 0);
        __builtin_amdgcn_s_setprio(0);
        __builtin_amdgcn_sched_barrier(0);
        __builtin_amdgcn_s_barrier();

        // ---- P3: 12 MFMA (Ah*Bh), no reads
        __builtin_amdgcn_s_setprio(1);
#pragma unroll
        for (int f = 0; f < 4; ++f)
#pragma unroll
            for (int g = 0; g < 3; ++g)
                acc1[f][g] = __builtin_amdgcn_mfma_f32_16x16x32_f16(fah[f], fgh[g], acc1[f][g], 0, 0, 0);
        __builtin_amdgcn_s_setprio(0);
        __builtin_amdgcn_sched_barrier(0);

        int t_ = b0; b0 = b1; b1 = b2; b2 = t_;
    }
#undef STAGE3

    float bv[3];
#pragma unroll
    for (int g = 0; g < 3; ++g) bv[g] = bias[n0 + wn + g * 16 + l16];

    if (MODE == 1) {
        // GELU + fp16 hi/lo split; smem round-trip, row stride 200 halves,
        // hi @0, lo @25600. (r7/r8-verified epilogue.)
        __syncthreads();
#pragma unroll
        for (int f = 0; f < 4; ++f)
#pragma unroll
            for (int g = 0; g < 3; ++g)
#pragma unroll
                for (int r = 0; r < 4; ++r) {
                    int rm = wm + f * 16 + quad * 4 + r;
                    int cn = wn + g * 16 + l16;
                    float v = acc1[f][g][r] + acc2[f][g][r] * LO_INV + bv[g];
                    v = 0.5f * v * (1.0f + erff(v * 0.70710678118654752f));
                    half_t hh = (half_t)v;
                    smem[rm * 200 + cn] = hh;
                    smem[25600 + rm * 200 + cn] = (half_t)((v - (float)hh) * LO_SCALE);
                }
        __syncthreads();
        int row = tid >> 2, c0 = (tid & 3) * 48;
        long go = (long)(m0 + row) * N + n0 + c0;
        int so = row * 200 + c0;
#pragma unroll
        for (int u = 0; u < 6; ++u) {
            *(float4*)(Ch + go + u * 8) = *(const float4*)&smem[so + u * 8];
            *(float4*)(Cl + go + u * 8) = *(const float4*)&smem[25600 + so + u * 8];
        }
    } else {
#pragma unroll
        for (int f = 0; f < 4; ++f)
#pragma unroll
            for (int g = 0; g < 3; ++g)
#pragma unroll
                for (int r = 0; r < 4; ++r) {
                    long row = m0 + wm + f * 16 + quad * 4 + r;
                    int col = n0 + wn + g * 16 + l16;
                    float v = acc1[f][g][r] + acc2[f][g][r] * LO_INV + bv[g];
                    long o = row * N + col;
                    if (MODE == 2) v += res[o];
                    Cf[o] = v;
                }
    }
}

// ---------------------------------------------------------------------------
// Fused out-conv (pointwise, C=8) + nearest-embedding argmin over K=8192
// ---------------------------------------------------------------------------
__global__ __launch_bounds__(256) void k_outconv_argmin(
    const float* __restrict__ h, const float* __restrict__ ow,
    const float* __restrict__ ob, const float* __restrict__ emb,
    int* __restrict__ outIdx) {
    __shared__ float hs[16][H_ + 1];
    __shared__ float zs[16][8];
    __shared__ float es[16 * 516];
    __shared__ float rb[16][16];
    __shared__ int ri[16][16];
    const int tid = threadIdx.x;
    const int row0 = blockIdx.x << 4;

    for (int i = tid; i < 16 * (H_ / 4); i += 256) {
        int r = i / 96;
        int c4 = (i % 96) << 2;
        float4 v = *(const float4*)&h[((long)(row0 + r)) * H_ + c4];
        hs[r][c4] = v.x; hs[r][c4 + 1] = v.y; hs[r][c4 + 2] = v.z; hs[r][c4 + 3] = v.w;
    }
    __syncthreads();

    if (tid < 128) {
        int r = tid & 15, c = tid >> 4;
        float acc = ob[c];
        const float* wc = ow + c * H_;
        for (int j = 0; j < H_; ++j) acc = fmaf(hs[r][j], wc[j], acc);
        zs[r][c] = acc;
    }
    __syncthreads();

    const int r = tid & 15;
    const int sl = tid >> 4;
    float z0 = zs[r][0], z1 = zs[r][1], z2 = zs[r][2], z3 = zs[r][3];
    float z4 = zs[r][4], z5 = zs[r][5], z6 = zs[r][6], z7 = zs[r][7];
    float best = 3.4e38f;
    int bi = 0;

    for (int ch = 0; ch < 8; ++ch) {
        __syncthreads();
        for (int i = tid; i < 2048; i += 256) {
            int e = i >> 1;
            int half = (i & 1) << 2;
            float4 src = *(const float4*)&emb[(((long)(ch << 10)) + e) * 8 + half];
            *(float4*)&es[(e >> 6) * 516 + ((e & 63) << 3) + half] = src;
        }
        __syncthreads();
        const float* ep = es + sl * 516;
        int gbase = (ch << 10) + (sl << 6);
#pragma unroll 4
        for (int j = 0; j < 64; ++j) {
            float4 e0 = *(const float4*)(ep + (j << 3));
            float4 e1 = *(const float4*)(ep + (j << 3) + 4);
            float t, d;
            t = e0.x - z0; d = t * t;
            t = e0.y - z1; d = fmaf(t, t, d);
            t = e0.z - z2; d = fmaf(t, t, d);
            t = e0.w - z3; d = fmaf(t, t, d);
            t = e1.x - z4; d = fmaf(t, t, d);
            t = e1.y - z5; d = fmaf(t, t, d);
            t = e1.z - z6; d = fmaf(t, t, d);
            t = e1.w - z7; d = fmaf(t, t, d);
            if (d < best) { best = d; bi = gbase + j; }
        }
    }
    rb[r][sl] = best;
    ri[r][sl] = bi;
    __syncthreads();
    if (sl == 0) {
        float bb = rb[r][0];
        int bbi = ri[r][0];
#pragma unroll
        for (int s2 = 1; s2 < 16; ++s2) {
            float v = rb[r][s2];
            int i2 = ri[r][s2];
            if (v < bb || (v == bb && i2 < bbi)) { bb = v; bbi = i2; }
        }
        outIdx[row0 + r] = bbi;
    }
}

// ---------------------------------------------------------------------------
// host launcher
// ---------------------------------------------------------------------------
extern "C" void kernel_launch(void* const* d_in, const int* in_sizes, int n_in,
                              void* d_out, int out_size, void* d_ws, size_t ws_size,
                              hipStream_t stream) {
    const float* x        = (const float*)d_in[0];
    const float* enc_w    = (const float*)d_in[1];
    const float* enc_b    = (const float*)d_in[2];
    const float* enc_ln_g = (const float*)d_in[3];
    const float* enc_ln_b = (const float*)d_in[4];
    const float* blk_dw_w = (const float*)d_in[5];
    const float* blk_dw_b = (const float*)d_in[6];
    const float* blk_ln_g = (const float*)d_in[7];
    const float* blk_ln_b = (const float*)d_in[8];
    const float* blk_w1   = (const float*)d_in[9];
    const float* blk_b1   = (const float*)d_in[10];
    const float* blk_w2   = (const float*)d_in[11];
    const float* blk_b2   = (const float*)d_in[12];
    const float* out_w    = (const float*)d_in[13];
    const float* out_b    = (const float*)d_in[14];
    const float* emb      = (const float*)d_in[15];
    int* out = (int*)d_out;

    char* base = (char*)d_ws;
    float*  h    = (float*)base;                       // 25165824 B
    half_t* tmph = (half_t*)(base + 25165824);         // 12582912 B
    half_t* tmpl = (half_t*)(base + 37748736);         // 12582912 B
    half_t* ht4h = (half_t*)(base + 50331648);         // 50331648 B
    half_t* ht4l = (half_t*)(base + 100663296);        // 50331648 B
    half_t* ench = (half_t*)(base + 150994944);        // 2752512 B
    half_t* encl = (half_t*)(base + 153747456);        // 2752512 B
    half_t* w1h  = (half_t*)(base + 156499968);        // 7077888 B
    half_t* w1l  = (half_t*)(base + 163577856);        // 7077888 B
    half_t* w2h  = (half_t*)(base + 170655744);        // 7077888 B
    half_t* w2l  = (half_t*)(base + 177733632);        // 7077888 B
    // padded x hi/lo (8 x 2054 x 512 halves = 16826368 B each) alias the
    // ht4 region (dead until first GEMM1)
    half_t* xph = (half_t*)(base + 50331648);
    half_t* xpl = (half_t*)(base + 50331648 + 16826368);

    k_split_pad<<<8216, 256, 0, stream>>>(x, xph, xpl);
    k_split4<<<3456, 256, 0, stream>>>(blk_w1, w1h, w1l, 884736L);
    k_split4<<<3456, 256, 0, stream>>>(blk_w2, w2h, w2l, 884736L);
    k_split_encw<<<(H_ * 3584 + 255) / 256, 256, 0, stream>>>(enc_w, ench, encl);

    // encoder conv as padded-im2row 3-phase GEMM -> h, then in-place LN.
    // Grid 128m x 2n = 256 blocks = exactly 1 round.
    k_g192p<0, 2><<<256, 512, 0, stream>>>(xph, xpl, ench, encl, enc_b,
                                           nullptr, h, nullptr, nullptr,
                                           H_, 3584);
    k_ln<<<BT_, 64, 0, stream>>>(h, h, enc_ln_g, enc_ln_b);

    for (int i = 0; i < 6; ++i) {
        k_dwconv_ln<<<BT_ / 4, 256, 0, stream>>>(h, tmph, tmpl, blk_dw_w + i * H_ * 7,
                                                 blk_dw_b + i * H_, blk_ln_g + i * H_,
                                                 blk_ln_b + i * H_);
        // GEMM1: 128x192 3-phase counted-vmcnt tiles; 128m x 8n = 1024 blocks
        k_g192p<1, 8><<<1024, 512, 0, stream>>>(
            tmph, tmpl, w1h + (long)i * 589824, w1l + (long)i * 589824,
            blk_b1 + i * H4_, nullptr, nullptr, ht4h, ht4l, H4_, H_);
        // GEMM2: 128x192 tiles; 128m x 2n = 256 blocks = 1 exact round
        k_g192p<2, 2><<<256, 512, 0, stream>>>(
            ht4h, ht4l, w2h + (long)i * 589824, w2l + (long)i * 589824,
            blk_b2 + i * H_, h, h, nullptr, nullptr, H_, H4_);
    }

    k_outconv_argmin<<<BT_ / 16, 256, 0, stream>>>(h, out_w, out_b, emb, out);
}

// Round 10
// 1647.116 us; speedup vs baseline: 1.0334x; 1.0334x over previous
//
#include <hip/hip_runtime.h>
#include <math.h>

#define T_   2048
#define DIN  512
#define H_   384
#define H4_  1536
#define BT_  16384

typedef _Float16 half_t;
typedef _Float16 f16x8 __attribute__((ext_vector_type(8)));
typedef _Float16 f16x4 __attribute__((ext_vector_type(4)));
typedef float f32x4 __attribute__((ext_vector_type(4)));

#define LO_SCALE 2048.0f
#define LO_INV   4.8828125e-4f

// async global->LDS DMA, 16 B per lane (1 KB per wave-instruction).
__device__ __forceinline__ void gload_lds(const half_t* g, half_t* l) {
    __builtin_amdgcn_global_load_lds(
        (const __attribute__((address_space(1))) unsigned int*)(const void*)g,
        (__attribute__((address_space(3))) unsigned int*)(void*)l, 16, 0, 0);
}

__device__ __forceinline__ void split2(float v, half_t* hi, half_t* lo) {
    half_t h = (half_t)v;
    *hi = h;
    *lo = (half_t)((v - (float)h) * LO_SCALE);
}

// ---------------------------------------------------------------------------
// fp32 -> (hi, lo*2048) fp16 split, 4 elems/thread (G13 vectorized)
// ---------------------------------------------------------------------------
__global__ void k_split4(const float* __restrict__ in, half_t* __restrict__ hi,
                         half_t* __restrict__ lo, long n4) {
    long i = (long)blockIdx.x * 256 + threadIdx.x;
    if (i >= n4) return;
    float4 v = ((const float4*)in)[i];
    f16x4 vh, vl;
    float a[4] = {v.x, v.y, v.z, v.w};
#pragma unroll
    for (int j = 0; j < 4; ++j) {
        half_t h = (half_t)a[j];
        vh[j] = h;
        vl[j] = (half_t)((a[j] - (float)h) * LO_SCALE);
    }
    ((f16x4*)hi)[i] = vh;
    ((f16x4*)lo)[i] = vl;
}

// ---------------------------------------------------------------------------
// t-padded split of x: xpad[b][u][ii] = x[b][u-3][ii] for u in [3,2051),
// zeros at pads; u in [0,2054). With the [tap*512+ii] K-ordering, im2row
// row (b,t) is the CONTIGUOUS 3584-half slice at (b*2054+t)*512
// (exact fit: 2047*512+3583 = 2054*512-1) -> encoder conv becomes a plain
// row-major GEMM (no bounds check -> DMA-stageable). r9-verified.
// ---------------------------------------------------------------------------
__global__ void k_split_pad(const float* __restrict__ in, half_t* __restrict__ hi,
                            half_t* __restrict__ lo) {
    long i = (long)blockIdx.x * 256 + threadIdx.x;   // 4-elem granule
    if (i >= 2103296L) return;                        // 8*2054*128
    int ii4 = (int)(i & 127);
    long rest = i >> 7;
    int u = (int)(rest % 2054);
    int b = (int)(rest / 2054);
    f16x4 vh = (f16x4)(half_t)0.f, vl = (f16x4)(half_t)0.f;
    if (u >= 3 && u < 2051) {
        float4 v = ((const float4*)in)[((long)b * 2048 + (u - 3)) * 128 + ii4];
        float a[4] = {v.x, v.y, v.z, v.w};
#pragma unroll
        for (int j = 0; j < 4; ++j) {
            half_t h = (half_t)a[j];
            vh[j] = h;
            vl[j] = (half_t)((a[j] - (float)h) * LO_SCALE);
        }
    }
    ((f16x4*)hi)[i] = vh;
    ((f16x4*)lo)[i] = vl;
}

// enc_w [H][DIN][7] -> [H][tap*512+i] hi/lo
__global__ void k_split_encw(const float* __restrict__ in, half_t* __restrict__ hi,
                             half_t* __restrict__ lo) {
    int idx = blockIdx.x * 256 + threadIdx.x;
    if (idx >= H_ * 3584) return;
    int n = idx / 3584;
    int r = idx % 3584;
    int tap = r >> 9, i = r & 511;
    split2(in[n * 3584 + i * 7 + tap], hi + idx, lo + idx);
}

// ---------------------------------------------------------------------------
// Row-wise LayerNorm over H=384 (fp32 in/out, in-place safe), one wave per row
// ---------------------------------------------------------------------------
__global__ void k_ln(const float* __restrict__ in, float* __restrict__ out,
                     const float* __restrict__ g, const float* __restrict__ b) {
    int row = blockIdx.x;
    int lane = threadIdx.x;
    const float* ir = in + (long)row * H_;
    float v[6];
    float s = 0.f;
#pragma unroll
    for (int j = 0; j < 6; ++j) { v[j] = ir[lane + (j << 6)]; s += v[j]; }
#pragma unroll
    for (int o = 32; o > 0; o >>= 1) s += __shfl_down(s, o, 64);
    s = __shfl(s, 0, 64);
    float mean = s * (1.f / 384.f);
    float q = 0.f;
#pragma unroll
    for (int j = 0; j < 6; ++j) { float d = v[j] - mean; q += d * d; }
#pragma unroll
    for (int o = 32; o > 0; o >>= 1) q += __shfl_down(q, o, 64);
    q = __shfl(q, 0, 64);
    float rstd = rsqrtf(q * (1.f / 384.f) + 1e-5f);
    float* orow = out + (long)row * H_;
#pragma unroll
    for (int j = 0; j < 6; ++j) {
        int c = lane + (j << 6);
        orow[c] = (v[j] - mean) * rstd * g[c] + b[c];
    }
}

// ---------------------------------------------------------------------------
// Fused depthwise conv (k=7, pad=3) + LayerNorm; emits fp16 hi/lo for GEMM1.
// float2-vectorized h loads (G13).
// ---------------------------------------------------------------------------
__global__ __launch_bounds__(256) void k_dwconv_ln(
    const float* __restrict__ h, half_t* __restrict__ oh,
    half_t* __restrict__ ol,
    const float* __restrict__ w, const float* __restrict__ wb,
    const float* __restrict__ g, const float* __restrict__ gb) {
    int row = (blockIdx.x << 2) + (threadIdx.x >> 6);
    int b = row >> 11;
    int t = row & 2047;
    int lane = threadIdx.x & 63;
    const float* hb = h + ((long)b * T_) * H_;
    float vx[3], vy[3];
    float s = 0.f;
#pragma unroll
    for (int j = 0; j < 3; ++j) {
        int c = (lane << 1) + (j << 7);
        float ax = wb[c], ay = wb[c + 1];
        const float* wcx = w + c * 7;
        const float* wcy = wcx + 7;
#pragma unroll
        for (int k = 0; k < 7; ++k) {
            int tt = t + k - 3;
            if ((unsigned)tt < (unsigned)T_) {
                float2 hv = *(const float2*)&hb[(long)tt * H_ + c];
                ax = fmaf(hv.x, wcx[k], ax);
                ay = fmaf(hv.y, wcy[k], ay);
            }
        }
        vx[j] = ax; vy[j] = ay;
        s += ax + ay;
    }
#pragma unroll
    for (int o = 32; o > 0; o >>= 1) s += __shfl_down(s, o, 64);
    s = __shfl(s, 0, 64);
    float mean = s * (1.f / 384.f);
    float q = 0.f;
#pragma unroll
    for (int j = 0; j < 3; ++j) {
        float dx = vx[j] - mean, dy = vy[j] - mean;
        q += dx * dx + dy * dy;
    }
#pragma unroll
    for (int o = 32; o > 0; o >>= 1) q += __shfl_down(q, o, 64);
    q = __shfl(q, 0, 64);
    float rstd = rsqrtf(q * (1.f / 384.f) + 1e-5f);
    long ro = (long)row * H_;
#pragma unroll
    for (int j = 0; j < 3; ++j) {
        int c = (lane << 1) + (j << 7);
        float valx = (vx[j] - mean) * rstd * g[c] + gb[c];
        float valy = (vy[j] - mean) * rstd * g[c + 1] + gb[c + 1];
        split2(valx, oh + ro + c, ol + ro + c);
        split2(valy, oh + ro + c + 1, ol + ro + c + 1);
    }
}

// ---------------------------------------------------------------------------
// MFMA fp16x3 GEMM "g192p": BM=128 x BN=192, BK=32, 512 threads = 8 waves
// (2m x 4n), wave tile 64x48. Ring-3 LDS (120 KB) + counted vmcnt(5).
// r10 change: ONE barrier per K-step (iter-start vmcnt+s_barrier only).
// The r8/r9 intra-iteration barriers were template cargo-cult: staging is
// DMA into b2 (unread this iter), so no intra-iter ordering is needed, and
// block-wide phase barriers were forcing all 8 waves into lockstep
// {LDS-burst, MFMA-burst} alternation (per-K-step: MFMA pipe needs ~1160
// cyc, LDS ~450, measured 2850 -> 41% util). Without them, waves skew and
// the two pipes overlap across waves. Ring safety unchanged: all reads of
// a buffer retire before the wave's next iter-start barrier; the DMA
// overwrite of that buffer issues after it. sched_barrier(0) after the
// barrier keeps ds_reads from hoisting above the publish point (rule #18);
// the "memory"-clobbered vmcnt asm fences sinking from below.
// MODE 0: A = padded im2row x (row stride 512, K=3584), +bias, fp32 out.
// MODE 1: +bias, exact GELU, fp16 hi/lo out (smem round-trip, stride 200)
// MODE 2: +bias, +res, fp32 out
// Buf layout (halves, stride 20480): Ahi@0 Alo@4096 Bhi@8192 Blo@14336.
// ---------------------------------------------------------------------------
template <int MODE, int NT>
__global__ __launch_bounds__(512, 2) void k_g192p(
    const half_t* __restrict__ Ah, const half_t* __restrict__ Al,
    const half_t* __restrict__ Bh, const half_t* __restrict__ Bl,
    const float* __restrict__ bias, const float* __restrict__ res,
    float* __restrict__ Cf, half_t* __restrict__ Ch, half_t* __restrict__ Cl,
    int N, int K) {
    __shared__ __align__(16) half_t smem[61440];
    const int tid = threadIdx.x;
    const int lane = tid & 63, wid = tid >> 6;
    const int wm = (wid & 1) << 6;          // {0, 64}
    const int wn = ((wid >> 1) & 3) * 48;   // {0, 48, 96, 144}
    const int quad = lane >> 4, l16 = lane & 15;

    constexpr int NWG = 128 * NT;
    constexpr int CHUNK = NWG / 8;
    const int lin = blockIdx.x;
    const int tile = (lin & 7) * CHUNK + (lin >> 3);
    const int m0 = (tile / NT) << 7;
    const int n0 = (tile % NT) * 192;

    // A row addressing: MODE 0 reads the padded im2row (stride 512,
    // base row b*2054 + t0); others are plain row-major stride K.
    long abase;
    int astr;
    if (MODE == 0) {
        abase = (long)(m0 >> 11) * 2054 + (m0 & 2047);
        astr = 512;
    } else {
        abase = m0;
        astr = K;
    }

    // per-lane DMA source swizzle (m173, r6-r9-verified)
    const int lr = lane >> 2;
    const int lg = (lane & 3) ^ ((lane >> 3) & 3);
    const half_t* gsrc[5];
    int ldo[5];
#pragma unroll
    for (int j = 0; j < 5; ++j) {
        int q = wid * 5 + j;
        if (q < 8) {
            gsrc[j] = Ah + (abase + q * 16 + lr) * (long)astr + lg * 8;
            ldo[j] = q * 512;
        } else if (q < 16) {
            gsrc[j] = Al + (abase + (q - 8) * 16 + lr) * (long)astr + lg * 8;
            ldo[j] = 4096 + (q - 8) * 512;
        } else if (q < 28) {
            gsrc[j] = Bh + ((long)(n0 + (q - 16) * 16 + lr)) * K + lg * 8;
            ldo[j] = 8192 + (q - 16) * 512;
        } else {
            gsrc[j] = Bl + ((long)(n0 + (q - 28) * 16 + lr)) * K + lg * 8;
            ldo[j] = 14336 + (q - 28) * 512;
        }
    }

#define STAGE3(bufb, k0_) do {                                              \
    int k0v = (k0_);                                                        \
    _Pragma("unroll")                                                       \
    for (int j = 0; j < 5; ++j)                                             \
        gload_lds(gsrc[j] + k0v, &smem[(bufb) + ldo[j]]);                   \
} while (0)

    f32x4 acc1[4][3] = {};
    f32x4 acc2[4][3] = {};
    const int sw = ((quad ^ (l16 >> 1)) & 3) << 3;

    const int nIter = K >> 5;   // 112 (enc) / 12 (G1) / 48 (G2); >= 3
    STAGE3(0, 0);
    STAGE3(20480, 32);
    int b0 = 0, b1 = 20480, b2 = 40960;
    for (int it = 0; it < nIter; ++it) {
        if (it + 1 < nIter)
            asm volatile("s_waitcnt vmcnt(5)" ::: "memory");
        else
            asm volatile("s_waitcnt vmcnt(0)" ::: "memory");
        __builtin_amdgcn_s_barrier();
        __builtin_amdgcn_sched_barrier(0);

        const int ab = b0 + (wm + l16) * 32 + sw;
        const int bb = b0 + 8192 + (wn + l16) * 32 + sw;
        const int k2 = (it + 2) << 5;
        const bool st = (it + 2 < nIter);
        f16x8 fah[4], fal[4], fgh[3], fgl[3];

        // ---- P1: Ah + Bl reads, 2/5 staging, 12 MFMA (Ah*Bl) — no barrier
#pragma unroll
        for (int f = 0; f < 4; ++f)
            fah[f] = *(const f16x8*)&smem[ab + f * 512];
#pragma unroll
        for (int g = 0; g < 3; ++g)
            fgl[g] = *(const f16x8*)&smem[bb + 6144 + g * 512];
        if (st) {
            gload_lds(gsrc[0] + k2, &smem[b2 + ldo[0]]);
            gload_lds(gsrc[1] + k2, &smem[b2 + ldo[1]]);
        }
        __builtin_amdgcn_s_setprio(1);
#pragma unroll
        for (int f = 0; f < 4; ++f)
#pragma unroll
            for (int g = 0; g < 3; ++g)
                acc2[f][g] = __builtin_amdgcn_mfma_f32_16x16x32_f16(fah[f], fgl[g], acc2[f][g], 0, 0, 0);
        __builtin_amdgcn_s_setprio(0);

        // ---- P2: Al + Bh reads, 3/5 staging, 12 MFMA (Al*Bh) — no barrier
#pragma unroll
        for (int f = 0; f < 4; ++f)
            fal[f] = *(const f16x8*)&smem[ab + 4096 + f * 512];
#pragma unroll
        for (int g = 0; g < 3; ++g)
            fgh[g] = *(const f16x8*)&smem[bb + g * 512];
        if (st) {
            gload_lds(gsrc[2] + k2, &smem[b2 + ldo[2]]);
            gload_lds(gsrc[3] + k2, &smem[b2 + ldo[3]]);
            gload_lds(gsrc[4] + k2, &smem[b2 + ldo[4]]);
        }
        __builtin_amdgcn_s_setprio(1);
#pragma unroll
        for (int f = 0; f < 4; ++f)
#pragma unroll
            for (int g = 0; g < 3; ++g)
                acc2[f][g] = __builtin_amdgcn_mfma_f32_16x16x32_f16(fal[f], fgh[g], acc2[f][g], 0, 0, 0);
        __builtin_amdgcn_s_setprio(0);

        // ---- P3: 12 MFMA (Ah*Bh), no reads
        __builtin_amdgcn_s_setprio(1);
#pragma unroll
        for (int f = 0; f < 4; ++f)
#pragma unroll
            for (int g = 0; g < 3; ++g)
                acc1[f][g] = __builtin_amdgcn_mfma_f32_16x16x32_f16(fah[f], fgh[g], acc1[f][g], 0, 0, 0);
        __builtin_amdgcn_s_setprio(0);

        int t_ = b0; b0 = b1; b1 = b2; b2 = t_;
    }
#undef STAGE3

    float bv[3];
#pragma unroll
    for (int g = 0; g < 3; ++g) bv[g] = bias[n0 + wn + g * 16 + l16];

    if (MODE == 1) {
        // GELU + fp16 hi/lo split; smem round-trip, row stride 200 halves,
        // hi @0, lo @25600. (r7-r9-verified epilogue.)
        __syncthreads();
#pragma unroll
        for (int f = 0; f < 4; ++f)
#pragma unroll
            for (int g = 0; g < 3; ++g)
#pragma unroll
                for (int r = 0; r < 4; ++r) {
                    int rm = wm + f * 16 + quad * 4 + r;
                    int cn = wn + g * 16 + l16;
                    float v = acc1[f][g][r] + acc2[f][g][r] * LO_INV + bv[g];
                    v = 0.5f * v * (1.0f + erff(v * 0.70710678118654752f));
                    half_t hh = (half_t)v;
                    smem[rm * 200 + cn] = hh;
                    smem[25600 + rm * 200 + cn] = (half_t)((v - (float)hh) * LO_SCALE);
                }
        __syncthreads();
        int row = tid >> 2, c0 = (tid & 3) * 48;
        long go = (long)(m0 + row) * N + n0 + c0;
        int so = row * 200 + c0;
#pragma unroll
        for (int u = 0; u < 6; ++u) {
            *(float4*)(Ch + go + u * 8) = *(const float4*)&smem[so + u * 8];
            *(float4*)(Cl + go + u * 8) = *(const float4*)&smem[25600 + so + u * 8];
        }
    } else {
#pragma unroll
        for (int f = 0; f < 4; ++f)
#pragma unroll
            for (int g = 0; g < 3; ++g)
#pragma unroll
                for (int r = 0; r < 4; ++r) {
                    long row = m0 + wm + f * 16 + quad * 4 + r;
                    int col = n0 + wn + g * 16 + l16;
                    float v = acc1[f][g][r] + acc2[f][g][r] * LO_INV + bv[g];
                    long o = row * N + col;
                    if (MODE == 2) v += res[o];
                    Cf[o] = v;
                }
    }
}

// ---------------------------------------------------------------------------
// Fused out-conv (pointwise, C=8) + nearest-embedding argmin over K=8192
// ---------------------------------------------------------------------------
__global__ __launch_bounds__(256) void k_outconv_argmin(
    const float* __restrict__ h, const float* __restrict__ ow,
    const float* __restrict__ ob, const float* __restrict__ emb,
    int* __restrict__ outIdx) {
    __shared__ float hs[16][H_ + 1];
    __shared__ float zs[16][8];
    __shared__ float es[16 * 516];
    __shared__ float rb[16][16];
    __shared__ int ri[16][16];
    const int tid = threadIdx.x;
    const int row0 = blockIdx.x << 4;

    for (int i = tid; i < 16 * (H_ / 4); i += 256) {
        int r = i / 96;
        int c4 = (i % 96) << 2;
        float4 v = *(const float4*)&h[((long)(row0 + r)) * H_ + c4];
        hs[r][c4] = v.x; hs[r][c4 + 1] = v.y; hs[r][c4 + 2] = v.z; hs[r][c4 + 3] = v.w;
    }
    __syncthreads();

    if (tid < 128) {
        int r = tid & 15, c = tid >> 4;
        float acc = ob[c];
        const float* wc = ow + c * H_;
        for (int j = 0; j < H_; ++j) acc = fmaf(hs[r][j], wc[j], acc);
        zs[r][c] = acc;
    }
    __syncthreads();

    const int r = tid & 15;
    const int sl = tid >> 4;
    float z0 = zs[r][0], z1 = zs[r][1], z2 = zs[r][2], z3 = zs[r][3];
    float z4 = zs[r][4], z5 = zs[r][5], z6 = zs[r][6], z7 = zs[r][7];
    float best = 3.4e38f;
    int bi = 0;

    for (int ch = 0; ch < 8; ++ch) {
        __syncthreads();
        for (int i = tid; i < 2048; i += 256) {
            int e = i >> 1;
            int half = (i & 1) << 2;
            float4 src = *(const float4*)&emb[(((long)(ch << 10)) + e) * 8 + half];
            *(float4*)&es[(e >> 6) * 516 + ((e & 63) << 3) + half] = src;
        }
        __syncthreads();
        const float* ep = es + sl * 516;
        int gbase = (ch << 10) + (sl << 6);
#pragma unroll 4
        for (int j = 0; j < 64; ++j) {
            float4 e0 = *(const float4*)(ep + (j << 3));
            float4 e1 = *(const float4*)(ep + (j << 3) + 4);
            float t, d;
            t = e0.x - z0; d = t * t;
            t = e0.y - z1; d = fmaf(t, t, d);
            t = e0.z - z2; d = fmaf(t, t, d);
            t = e0.w - z3; d = fmaf(t, t, d);
            t = e1.x - z4; d = fmaf(t, t, d);
            t = e1.y - z5; d = fmaf(t, t, d);
            t = e1.z - z6; d = fmaf(t, t, d);
            t = e1.w - z7; d = fmaf(t, t, d);
            if (d < best) { best = d; bi = gbase + j; }
        }
    }
    rb[r][sl] = best;
    ri[r][sl] = bi;
    __syncthreads();
    if (sl == 0) {
        float bb = rb[r][0];
        int bbi = ri[r][0];
#pragma unroll
        for (int s2 = 1; s2 < 16; ++s2) {
            float v = rb[r][s2];
            int i2 = ri[r][s2];
            if (v < bb || (v == bb && i2 < bbi)) { bb = v; bbi = i2; }
        }
        outIdx[row0 + r] = bbi;
    }
}

// ---------------------------------------------------------------------------
// host launcher
// ---------------------------------------------------------------------------
extern "C" void kernel_launch(void* const* d_in, const int* in_sizes, int n_in,
                              void* d_out, int out_size, void* d_ws, size_t ws_size,
                              hipStream_t stream) {
    const float* x        = (const float*)d_in[0];
    const float* enc_w    = (const float*)d_in[1];
    const float* enc_b    = (const float*)d_in[2];
    const float* enc_ln_g = (const float*)d_in[3];
    const float* enc_ln_b = (const float*)d_in[4];
    const float* blk_dw_w = (const float*)d_in[5];
    const float* blk_dw_b = (const float*)d_in[6];
    const float* blk_ln_g = (const float*)d_in[7];
    const float* blk_ln_b = (const float*)d_in[8];
    const float* blk_w1   = (const float*)d_in[9];
    const float* blk_b1   = (const float*)d_in[10];
    const float* blk_w2   = (const float*)d_in[11];
    const float* blk_b2   = (const float*)d_in[12];
    const float* out_w    = (const float*)d_in[13];
    const float* out_b    = (const float*)d_in[14];
    const float* emb      = (const float*)d_in[15];
    int* out = (int*)d_out;

    char* base = (char*)d_ws;
    float*  h    = (float*)base;                       // 25165824 B
    half_t* tmph = (half_t*)(base + 25165824);         // 12582912 B
    half_t* tmpl = (half_t*)(base + 37748736);         // 12582912 B
    half_t* ht4h = (half_t*)(base + 50331648);         // 50331648 B
    half_t* ht4l = (half_t*)(base + 100663296);        // 50331648 B
    half_t* ench = (half_t*)(base + 150994944);        // 2752512 B
    half_t* encl = (half_t*)(base + 153747456);        // 2752512 B
    half_t* w1h  = (half_t*)(base + 156499968);        // 7077888 B
    half_t* w1l  = (half_t*)(base + 163577856);        // 7077888 B
    half_t* w2h  = (half_t*)(base + 170655744);        // 7077888 B
    half_t* w2l  = (half_t*)(base + 177733632);        // 7077888 B
    // padded x hi/lo (8 x 2054 x 512 halves = 16826368 B each) alias the
    // ht4 region (dead until first GEMM1)
    half_t* xph = (half_t*)(base + 50331648);
    half_t* xpl = (half_t*)(base + 50331648 + 16826368);

    k_split_pad<<<8216, 256, 0, stream>>>(x, xph, xpl);
    k_split4<<<3456, 256, 0, stream>>>(blk_w1, w1h, w1l, 884736L);
    k_split4<<<3456, 256, 0, stream>>>(blk_w2, w2h, w2l, 884736L);
    k_split_encw<<<(H_ * 3584 + 255) / 256, 256, 0, stream>>>(enc_w, ench, encl);

    // encoder conv as padded-im2row 3-phase GEMM -> h, then in-place LN.
    k_g192p<0, 2><<<256, 512, 0, stream>>>(xph, xpl, ench, encl, enc_b,
                                           nullptr, h, nullptr, nullptr,
                                           H_, 3584);
    k_ln<<<BT_, 64, 0, stream>>>(h, h, enc_ln_g, enc_ln_b);

    for (int i = 0; i < 6; ++i) {
        k_dwconv_ln<<<BT_ / 4, 256, 0, stream>>>(h, tmph, tmpl, blk_dw_w + i * H_ * 7,
                                                 blk_dw_b + i * H_, blk_ln_g + i * H_,
                                                 blk_ln_b + i * H_);
        // GEMM1: 128x192 tiles; 128m x 8n = 1024 blocks
        k_g192p<1, 8><<<1024, 512, 0, stream>>>(
            tmph, tmpl, w1h + (long)i * 589824, w1l + (long)i * 589824,
            blk_b1 + i * H4_, nullptr, nullptr, ht4h, ht4l, H4_, H_);
        // GEMM2: 128x192 tiles; 128m x 2n = 256 blocks = 1 exact round
        k_g192p<2, 2><<<256, 512, 0, stream>>>(
            ht4h, ht4l, w2h + (long)i * 589824, w2l + (long)i * 589824,
            blk_b2 + i * H_, h, h, nullptr, nullptr, H_, H4_);
    }

    k_outconv_argmin<<<BT_ / 16, 256, 0, stream>>>(h, out_w, out_b, emb, out);
}

// Round 11
// 1638.751 us; speedup vs baseline: 1.0386x; 1.0051x over previous
//
#include <hip/hip_runtime.h>
#include <math.h>

#define T_   2048
#define DIN  512
#define H_   384
#define H4_  1536
#define BT_  16384

typedef _Float16 half_t;
typedef _Float16 f16x8 __attribute__((ext_vector_type(8)));
typedef _Float16 f16x4 __attribute__((ext_vector_type(4)));
typedef float f32x4 __attribute__((ext_vector_type(4)));

#define LO_SCALE 2048.0f
#define LO_INV   4.8828125e-4f

// async global->LDS DMA, 16 B per lane (1 KB per wave-instruction).
__device__ __forceinline__ void gload_lds(const half_t* g, half_t* l) {
    __builtin_amdgcn_global_load_lds(
        (const __attribute__((address_space(1))) unsigned int*)(const void*)g,
        (__attribute__((address_space(3))) unsigned int*)(void*)l, 16, 0, 0);
}

__device__ __forceinline__ void split2(float v, half_t* hi, half_t* lo) {
    half_t h = (half_t)v;
    *hi = h;
    *lo = (half_t)((v - (float)h) * LO_SCALE);
}

// ---------------------------------------------------------------------------
// fp32 -> (hi, lo*2048) fp16 split, 4 elems/thread (G13 vectorized)
// ---------------------------------------------------------------------------
__global__ void k_split4(const float* __restrict__ in, half_t* __restrict__ hi,
                         half_t* __restrict__ lo, long n4) {
    long i = (long)blockIdx.x * 256 + threadIdx.x;
    if (i >= n4) return;
    float4 v = ((const float4*)in)[i];
    f16x4 vh, vl;
    float a[4] = {v.x, v.y, v.z, v.w};
#pragma unroll
    for (int j = 0; j < 4; ++j) {
        half_t h = (half_t)a[j];
        vh[j] = h;
        vl[j] = (half_t)((a[j] - (float)h) * LO_SCALE);
    }
    ((f16x4*)hi)[i] = vh;
    ((f16x4*)lo)[i] = vl;
}

// ---------------------------------------------------------------------------
// t-padded split of x: xpad[b][u][ii] = x[b][u-3][ii] for u in [3,2051),
// zeros at pads; u in [0,2054). Makes im2row row (b,t) a CONTIGUOUS
// 3584-half slice at (b*2054+t)*512 -> plain row-major GEMM. r9-verified.
// ---------------------------------------------------------------------------
__global__ void k_split_pad(const float* __restrict__ in, half_t* __restrict__ hi,
                            half_t* __restrict__ lo) {
    long i = (long)blockIdx.x * 256 + threadIdx.x;   // 4-elem granule
    if (i >= 2103296L) return;                        // 8*2054*128
    int ii4 = (int)(i & 127);
    long rest = i >> 7;
    int u = (int)(rest % 2054);
    int b = (int)(rest / 2054);
    f16x4 vh = (f16x4)(half_t)0.f, vl = (f16x4)(half_t)0.f;
    if (u >= 3 && u < 2051) {
        float4 v = ((const float4*)in)[((long)b * 2048 + (u - 3)) * 128 + ii4];
        float a[4] = {v.x, v.y, v.z, v.w};
#pragma unroll
        for (int j = 0; j < 4; ++j) {
            half_t h = (half_t)a[j];
            vh[j] = h;
            vl[j] = (half_t)((a[j] - (float)h) * LO_SCALE);
        }
    }
    ((f16x4*)hi)[i] = vh;
    ((f16x4*)lo)[i] = vl;
}

// enc_w [H][DIN][7] -> [H][tap*512+i] hi/lo
__global__ void k_split_encw(const float* __restrict__ in, half_t* __restrict__ hi,
                             half_t* __restrict__ lo) {
    int idx = blockIdx.x * 256 + threadIdx.x;
    if (idx >= H_ * 3584) return;
    int n = idx / 3584;
    int r = idx % 3584;
    int tap = r >> 9, i = r & 511;
    split2(in[n * 3584 + i * 7 + tap], hi + idx, lo + idx);
}

// ---------------------------------------------------------------------------
// Row-wise LayerNorm over H=384, 4 rows per 256-thread block (one wave/row).
// ---------------------------------------------------------------------------
__global__ __launch_bounds__(256) void k_ln(
    const float* __restrict__ in, float* __restrict__ out,
    const float* __restrict__ g, const float* __restrict__ b) {
    int row = (blockIdx.x << 2) + (threadIdx.x >> 6);
    int lane = threadIdx.x & 63;
    const float* ir = in + (long)row * H_;
    float v[6];
    float s = 0.f;
#pragma unroll
    for (int j = 0; j < 6; ++j) { v[j] = ir[lane + (j << 6)]; s += v[j]; }
#pragma unroll
    for (int o = 32; o > 0; o >>= 1) s += __shfl_down(s, o, 64);
    s = __shfl(s, 0, 64);
    float mean = s * (1.f / 384.f);
    float q = 0.f;
#pragma unroll
    for (int j = 0; j < 6; ++j) { float d = v[j] - mean; q += d * d; }
#pragma unroll
    for (int o = 32; o > 0; o >>= 1) q += __shfl_down(q, o, 64);
    q = __shfl(q, 0, 64);
    float rstd = rsqrtf(q * (1.f / 384.f) + 1e-5f);
    float* orow = out + (long)row * H_;
#pragma unroll
    for (int j = 0; j < 6; ++j) {
        int c = lane + (j << 6);
        orow[c] = (v[j] - mean) * rstd * g[c] + b[c];
    }
}

// ---------------------------------------------------------------------------
// Fused depthwise conv (k=7, pad=3) + LayerNorm; emits fp16 hi/lo for GEMM1.
// float2-vectorized h loads (G13).
// ---------------------------------------------------------------------------
__global__ __launch_bounds__(256) void k_dwconv_ln(
    const float* __restrict__ h, half_t* __restrict__ oh,
    half_t* __restrict__ ol,
    const float* __restrict__ w, const float* __restrict__ wb,
    const float* __restrict__ g, const float* __restrict__ gb) {
    int row = (blockIdx.x << 2) + (threadIdx.x >> 6);
    int b = row >> 11;
    int t = row & 2047;
    int lane = threadIdx.x & 63;
    const float* hb = h + ((long)b * T_) * H_;
    float vx[3], vy[3];
    float s = 0.f;
#pragma unroll
    for (int j = 0; j < 3; ++j) {
        int c = (lane << 1) + (j << 7);
        float ax = wb[c], ay = wb[c + 1];
        const float* wcx = w + c * 7;
        const float* wcy = wcx + 7;
#pragma unroll
        for (int k = 0; k < 7; ++k) {
            int tt = t + k - 3;
            if ((unsigned)tt < (unsigned)T_) {
                float2 hv = *(const float2*)&hb[(long)tt * H_ + c];
                ax = fmaf(hv.x, wcx[k], ax);
                ay = fmaf(hv.y, wcy[k], ay);
            }
        }
        vx[j] = ax; vy[j] = ay;
        s += ax + ay;
    }
#pragma unroll
    for (int o = 32; o > 0; o >>= 1) s += __shfl_down(s, o, 64);
    s = __shfl(s, 0, 64);
    float mean = s * (1.f / 384.f);
    float q = 0.f;
#pragma unroll
    for (int j = 0; j < 3; ++j) {
        float dx = vx[j] - mean, dy = vy[j] - mean;
        q += dx * dx + dy * dy;
    }
#pragma unroll
    for (int o = 32; o > 0; o >>= 1) q += __shfl_down(q, o, 64);
    q = __shfl(q, 0, 64);
    float rstd = rsqrtf(q * (1.f / 384.f) + 1e-5f);
    long ro = (long)row * H_;
#pragma unroll
    for (int j = 0; j < 3; ++j) {
        int c = (lane << 1) + (j << 7);
        float valx = (vx[j] - mean) * rstd * g[c] + gb[c];
        float valy = (vy[j] - mean) * rstd * g[c + 1] + gb[c + 1];
        split2(valx, oh + ro + c, ol + ro + c);
        split2(valy, oh + ro + c + 1, ol + ro + c + 1);
    }
}

// ---------------------------------------------------------------------------
// MFMA fp16x3 GEMM "g192p": BM=128 x BN=192, BK=32, 512 threads = 8 waves
// (2m x 4n), wave tile 64x48. Ring-3 LDS (120 KB) + counted vmcnt(5) +
// ONE barrier/K-step (r10-verified: 117 us enc, MfmaUtil 54%).
// r11 change: WAVE-PHASE STAGGER. Per-SIMD arithmetic at r10: MFMA floor
// 1484 cyc/K-step, LDS+VALU ~840, measured 2507 ~= zero overlap -- the 2
// waves/SIMD (w and w+4) leave the barrier in phase and read-burst
// together, starving the MFMA pipe. Waves 4-7 now execute the two product
// halves in the opposite order (read Al+Bh first): one wave's MFMA cluster
// overlays its SIMD-partner's read burst. Both orders accumulate acc2
// identically-validly; the Ah*Bh cluster picks whichever frags are live.
// DMA issue points stay position-attached (2 then 3) -> vmcnt unchanged.
// r11 also: MODE 0/2 epilogue via fp32 smem round-trip -> float4 stores
// and float4 res loads (was scattered 4 B).
// MODE 0: A = padded im2row x (row stride 512, K=3584), +bias, fp32 out.
// MODE 1: +bias, exact GELU, fp16 hi/lo out (smem round-trip, stride 200)
// MODE 2: +bias, +res, fp32 out
// Buf layout (halves, stride 20480): Ahi@0 Alo@4096 Bhi@8192 Blo@14336.
// ---------------------------------------------------------------------------
#define KHALF1(AOFF, BOFF, F1A, F1B)                                        \
    _Pragma("unroll")                                                       \
    for (int f = 0; f < 4; ++f)                                             \
        F1A[f] = *(const f16x8*)&smem[ab + (AOFF) + f * 512];               \
    _Pragma("unroll")                                                       \
    for (int g = 0; g < 3; ++g)                                             \
        F1B[g] = *(const f16x8*)&smem[bb + (BOFF) + g * 512];               \
    if (st) {                                                               \
        gload_lds(gsrc[0] + k2, &smem[b2 + ldo[0]]);                        \
        gload_lds(gsrc[1] + k2, &smem[b2 + ldo[1]]);                        \
    }                                                                       \
    __builtin_amdgcn_s_setprio(1);                                          \
    _Pragma("unroll")                                                       \
    for (int f = 0; f < 4; ++f)                                             \
        _Pragma("unroll")                                                   \
        for (int g = 0; g < 3; ++g)                                         \
            acc2[f][g] = __builtin_amdgcn_mfma_f32_16x16x32_f16(            \
                F1A[f], F1B[g], acc2[f][g], 0, 0, 0);                       \
    __builtin_amdgcn_s_setprio(0);

#define KHALF2(AOFF, BOFF, F2A, F2B)                                        \
    _Pragma("unroll")                                                       \
    for (int f = 0; f < 4; ++f)                                             \
        F2A[f] = *(const f16x8*)&smem[ab + (AOFF) + f * 512];               \
    _Pragma("unroll")                                                       \
    for (int g = 0; g < 3; ++g)                                             \
        F2B[g] = *(const f16x8*)&smem[bb + (BOFF) + g * 512];               \
    if (st) {                                                               \
        gload_lds(gsrc[2] + k2, &smem[b2 + ldo[2]]);                        \
        gload_lds(gsrc[3] + k2, &smem[b2 + ldo[3]]);                        \
        gload_lds(gsrc[4] + k2, &smem[b2 + ldo[4]]);                        \
    }                                                                       \
    __builtin_amdgcn_s_setprio(1);                                          \
    _Pragma("unroll")                                                       \
    for (int f = 0; f < 4; ++f)                                             \
        _Pragma("unroll")                                                   \
        for (int g = 0; g < 3; ++g)                                         \
            acc2[f][g] = __builtin_amdgcn_mfma_f32_16x16x32_f16(            \
                F2A[f], F2B[g], acc2[f][g], 0, 0, 0);                       \
    __builtin_amdgcn_s_setprio(0);

#define KHI(FAH, FGH)                                                       \
    __builtin_amdgcn_s_setprio(1);                                          \
    _Pragma("unroll")                                                       \
    for (int f = 0; f < 4; ++f)                                             \
        _Pragma("unroll")                                                   \
        for (int g = 0; g < 3; ++g)                                         \
            acc1[f][g] = __builtin_amdgcn_mfma_f32_16x16x32_f16(            \
                FAH[f], FGH[g], acc1[f][g], 0, 0, 0);                       \
    __builtin_amdgcn_s_setprio(0);

template <int MODE, int NT>
__global__ __launch_bounds__(512, 2) void k_g192p(
    const half_t* __restrict__ Ah, const half_t* __restrict__ Al,
    const half_t* __restrict__ Bh, const half_t* __restrict__ Bl,
    const float* __restrict__ bias, const float* __restrict__ res,
    float* __restrict__ Cf, half_t* __restrict__ Ch, half_t* __restrict__ Cl,
    int N, int K) {
    __shared__ __align__(16) half_t smem[61440];
    const int tid = threadIdx.x;
    const int lane = tid & 63, wid = tid >> 6;
    const int wm = (wid & 1) << 6;          // {0, 64}
    const int wn = ((wid >> 1) & 3) * 48;   // {0, 48, 96, 144}
    const int quad = lane >> 4, l16 = lane & 15;
    // waves w and w+4 share a SIMD -> stagger on bit 2 of wid
    const bool flip = (wid >> 2) & 1;

    constexpr int NWG = 128 * NT;
    constexpr int CHUNK = NWG / 8;
    const int lin = blockIdx.x;
    const int tile = (lin & 7) * CHUNK + (lin >> 3);
    const int m0 = (tile / NT) << 7;
    const int n0 = (tile % NT) * 192;

    long abase;
    int astr;
    if (MODE == 0) {
        abase = (long)(m0 >> 11) * 2054 + (m0 & 2047);
        astr = 512;
    } else {
        abase = m0;
        astr = K;
    }

    // per-lane DMA source swizzle (m173, r6-r10-verified)
    const int lr = lane >> 2;
    const int lg = (lane & 3) ^ ((lane >> 3) & 3);
    const half_t* gsrc[5];
    int ldo[5];
#pragma unroll
    for (int j = 0; j < 5; ++j) {
        int q = wid * 5 + j;
        if (q < 8) {
            gsrc[j] = Ah + (abase + q * 16 + lr) * (long)astr + lg * 8;
            ldo[j] = q * 512;
        } else if (q < 16) {
            gsrc[j] = Al + (abase + (q - 8) * 16 + lr) * (long)astr + lg * 8;
            ldo[j] = 4096 + (q - 8) * 512;
        } else if (q < 28) {
            gsrc[j] = Bh + ((long)(n0 + (q - 16) * 16 + lr)) * K + lg * 8;
            ldo[j] = 8192 + (q - 16) * 512;
        } else {
            gsrc[j] = Bl + ((long)(n0 + (q - 28) * 16 + lr)) * K + lg * 8;
            ldo[j] = 14336 + (q - 28) * 512;
        }
    }

#define STAGE3(bufb, k0_) do {                                              \
    int k0v = (k0_);                                                        \
    _Pragma("unroll")                                                       \
    for (int j = 0; j < 5; ++j)                                             \
        gload_lds(gsrc[j] + k0v, &smem[(bufb) + ldo[j]]);                   \
} while (0)

    f32x4 acc1[4][3] = {};
    f32x4 acc2[4][3] = {};
    const int sw = ((quad ^ (l16 >> 1)) & 3) << 3;

    const int nIter = K >> 5;   // 112 (enc) / 12 (G1) / 48 (G2); >= 3
    STAGE3(0, 0);
    STAGE3(20480, 32);
    int b0 = 0, b1 = 20480, b2 = 40960;
    for (int it = 0; it < nIter; ++it) {
        if (it + 1 < nIter)
            asm volatile("s_waitcnt vmcnt(5)" ::: "memory");
        else
            asm volatile("s_waitcnt vmcnt(0)" ::: "memory");
        __builtin_amdgcn_s_barrier();
        __builtin_amdgcn_sched_barrier(0);

        const int ab = b0 + (wm + l16) * 32 + sw;
        const int bb = b0 + 8192 + (wn + l16) * 32 + sw;
        const int k2 = (it + 2) << 5;
        const bool st = (it + 2 < nIter);

        if (!flip) {
            // order: (Ah,Bl) -> (Al,Bh) -> (Ah,Bh)
            f16x8 f1a[4], f1b[3], f2a[4], f2b[3];
            KHALF1(0, 6144, f1a, f1b)        // Ah * Bl
            KHALF2(4096, 0, f2a, f2b)        // Al * Bh
            KHI(f1a, f2b)                    // Ah * Bh
        } else {
            // order: (Al,Bh) -> (Ah,Bl) -> (Ah,Bh)
            f16x8 f1a[4], f1b[3], f2a[4], f2b[3];
            KHALF1(4096, 0, f1a, f1b)        // Al * Bh
            KHALF2(0, 6144, f2a, f2b)        // Ah * Bl
            KHI(f2a, f1b)                    // Ah * Bh
        }

        int t_ = b0; b0 = b1; b1 = b2; b2 = t_;
    }
#undef STAGE3

    float bv[3];
#pragma unroll
    for (int g = 0; g < 3; ++g) bv[g] = bias[n0 + wn + g * 16 + l16];

    if (MODE == 1) {
        // GELU + fp16 hi/lo split; smem round-trip, row stride 200 halves,
        // hi @0, lo @25600. (r7-r10-verified epilogue.)
        __syncthreads();
#pragma unroll
        for (int f = 0; f < 4; ++f)
#pragma unroll
            for (int g = 0; g < 3; ++g)
#pragma unroll
                for (int r = 0; r < 4; ++r) {
                    int rm = wm + f * 16 + quad * 4 + r;
                    int cn = wn + g * 16 + l16;
                    float v = acc1[f][g][r] + acc2[f][g][r] * LO_INV + bv[g];
                    v = 0.5f * v * (1.0f + erff(v * 0.70710678118654752f));
                    half_t hh = (half_t)v;
                    smem[rm * 200 + cn] = hh;
                    smem[25600 + rm * 200 + cn] = (half_t)((v - (float)hh) * LO_SCALE);
                }
        __syncthreads();
        int row = tid >> 2, c0 = (tid & 3) * 48;
        long go = (long)(m0 + row) * N + n0 + c0;
        int so = row * 200 + c0;
#pragma unroll
        for (int u = 0; u < 6; ++u) {
            *(float4*)(Ch + go + u * 8) = *(const float4*)&smem[so + u * 8];
            *(float4*)(Cl + go + u * 8) = *(const float4*)&smem[25600 + so + u * 8];
        }
    } else {
        // r11: fp32 smem round-trip -> coalesced float4 stores + res loads.
        // Tile [128][196] floats = 100332 B <= 122880 B LDS.
        __syncthreads();
        float* smemf = (float*)smem;
#pragma unroll
        for (int f = 0; f < 4; ++f)
#pragma unroll
            for (int g = 0; g < 3; ++g)
#pragma unroll
                for (int r = 0; r < 4; ++r) {
                    int rm = wm + f * 16 + quad * 4 + r;
                    int cn = wn + g * 16 + l16;
                    smemf[rm * 196 + cn] =
                        acc1[f][g][r] + acc2[f][g][r] * LO_INV + bv[g];
                }
        __syncthreads();
        int row = tid >> 2, c0 = (tid & 3) * 48;
        long go = (long)(m0 + row) * N + n0 + c0;
        int so = row * 196 + c0;
#pragma unroll
        for (int u = 0; u < 12; ++u) {
            float4 v = *(const float4*)&smemf[so + u * 4];
            if (MODE == 2) {
                float4 rr = *(const float4*)(res + go + u * 4);
                v.x += rr.x; v.y += rr.y; v.z += rr.z; v.w += rr.w;
            }
            *(float4*)(Cf + go + u * 4) = v;
        }
    }
}

// ---------------------------------------------------------------------------
// Fused out-conv (pointwise, C=8) + nearest-embedding argmin over K=8192
// ---------------------------------------------------------------------------
__global__ __launch_bounds__(256) void k_outconv_argmin(
    const float* __restrict__ h, const float* __restrict__ ow,
    const float* __restrict__ ob, const float* __restrict__ emb,
    int* __restrict__ outIdx) {
    __shared__ float hs[16][H_ + 1];
    __shared__ float zs[16][8];
    __shared__ float es[16 * 516];
    __shared__ float rb[16][16];
    __shared__ int ri[16][16];
    const int tid = threadIdx.x;
    const int row0 = blockIdx.x << 4;

    for (int i = tid; i < 16 * (H_ / 4); i += 256) {
        int r = i / 96;
        int c4 = (i % 96) << 2;
        float4 v = *(const float4*)&h[((long)(row0 + r)) * H_ + c4];
        hs[r][c4] = v.x; hs[r][c4 + 1] = v.y; hs[r][c4 + 2] = v.z; hs[r][c4 + 3] = v.w;
    }
    __syncthreads();

    if (tid < 128) {
        int r = tid & 15, c = tid >> 4;
        float acc = ob[c];
        const float* wc = ow + c * H_;
        for (int j = 0; j < H_; ++j) acc = fmaf(hs[r][j], wc[j], acc);
        zs[r][c] = acc;
    }
    __syncthreads();

    const int r = tid & 15;
    const int sl = tid >> 4;
    float z0 = zs[r][0], z1 = zs[r][1], z2 = zs[r][2], z3 = zs[r][3];
    float z4 = zs[r][4], z5 = zs[r][5], z6 = zs[r][6], z7 = zs[r][7];
    float best = 3.4e38f;
    int bi = 0;

    for (int ch = 0; ch < 8; ++ch) {
        __syncthreads();
        for (int i = tid; i < 2048; i += 256) {
            int e = i >> 1;
            int half = (i & 1) << 2;
            float4 src = *(const float4*)&emb[(((long)(ch << 10)) + e) * 8 + half];
            *(float4*)&es[(e >> 6) * 516 + ((e & 63) << 3) + half] = src;
        }
        __syncthreads();
        const float* ep = es + sl * 516;
        int gbase = (ch << 10) + (sl << 6);
#pragma unroll 4
        for (int j = 0; j < 64; ++j) {
            float4 e0 = *(const float4*)(ep + (j << 3));
            float4 e1 = *(const float4*)(ep + (j << 3) + 4);
            float t, d;
            t = e0.x - z0; d = t * t;
            t = e0.y - z1; d = fmaf(t, t, d);
            t = e0.z - z2; d = fmaf(t, t, d);
            t = e0.w - z3; d = fmaf(t, t, d);
            t = e1.x - z4; d = fmaf(t, t, d);
            t = e1.y - z5; d = fmaf(t, t, d);
            t = e1.z - z6; d = fmaf(t, t, d);
            t = e1.w - z7; d = fmaf(t, t, d);
            if (d < best) { best = d; bi = gbase + j; }
        }
    }
    rb[r][sl] = best;
    ri[r][sl] = bi;
    __syncthreads();
    if (sl == 0) {
        float bb = rb[r][0];
        int bbi = ri[r][0];
#pragma unroll
        for (int s2 = 1; s2 < 16; ++s2) {
            float v = rb[r][s2];
            int i2 = ri[r][s2];
            if (v < bb || (v == bb && i2 < bbi)) { bb = v; bbi = i2; }
        }
        outIdx[row0 + r] = bbi;
    }
}

// ---------------------------------------------------------------------------
// host launcher
// ---------------------------------------------------------------------------
extern "C" void kernel_launch(void* const* d_in, const int* in_sizes, int n_in,
                              void* d_out, int out_size, void* d_ws, size_t ws_size,
                              hipStream_t stream) {
    const float* x        = (const float*)d_in[0];
    const float* enc_w    = (const float*)d_in[1];
    const float* enc_b    = (const float*)d_in[2];
    const float* enc_ln_g = (const float*)d_in[3];
    const float* enc_ln_b = (const float*)d_in[4];
    const float* blk_dw_w = (const float*)d_in[5];
    const float* blk_dw_b = (const float*)d_in[6];
    const float* blk_ln_g = (const float*)d_in[7];
    const float* blk_ln_b = (const float*)d_in[8];
    const float* blk_w1   = (const float*)d_in[9];
    const float* blk_b1   = (const float*)d_in[10];
    const float* blk_w2   = (const float*)d_in[11];
    const float* blk_b2   = (const float*)d_in[12];
    const float* out_w    = (const float*)d_in[13];
    const float* out_b    = (const float*)d_in[14];
    const float* emb      = (const float*)d_in[15];
    int* out = (int*)d_out;

    char* base = (char*)d_ws;
    float*  h    = (float*)base;                       // 25165824 B
    half_t* tmph = (half_t*)(base + 25165824);         // 12582912 B
    half_t* tmpl = (half_t*)(base + 37748736);         // 12582912 B
    half_t* ht4h = (half_t*)(base + 50331648);         // 50331648 B
    half_t* ht4l = (half_t*)(base + 100663296);        // 50331648 B
    half_t* ench = (half_t*)(base + 150994944);        // 2752512 B
    half_t* encl = (half_t*)(base + 153747456);        // 2752512 B
    half_t* w1h  = (half_t*)(base + 156499968);        // 7077888 B
    half_t* w1l  = (half_t*)(base + 163577856);        // 7077888 B
    half_t* w2h  = (half_t*)(base + 170655744);        // 7077888 B
    half_t* w2l  = (half_t*)(base + 177733632);        // 7077888 B
    // padded x hi/lo (8 x 2054 x 512 halves = 16826368 B each) alias the
    // ht4 region (dead until first GEMM1)
    half_t* xph = (half_t*)(base + 50331648);
    half_t* xpl = (half_t*)(base + 50331648 + 16826368);

    k_split_pad<<<8216, 256, 0, stream>>>(x, xph, xpl);
    k_split4<<<3456, 256, 0, stream>>>(blk_w1, w1h, w1l, 884736L);
    k_split4<<<3456, 256, 0, stream>>>(blk_w2, w2h, w2l, 884736L);
    k_split_encw<<<(H_ * 3584 + 255) / 256, 256, 0, stream>>>(enc_w, ench, encl);

    // encoder conv as padded-im2row 3-phase GEMM -> h, then in-place LN.
    k_g192p<0, 2><<<256, 512, 0, stream>>>(xph, xpl, ench, encl, enc_b,
                                           nullptr, h, nullptr, nullptr,
                                           H_, 3584);
    k_ln<<<BT_ / 4, 256, 0, stream>>>(h, h, enc_ln_g, enc_ln_b);

    for (int i = 0; i < 6; ++i) {
        k_dwconv_ln<<<BT_ / 4, 256, 0, stream>>>(h, tmph, tmpl, blk_dw_w + i * H_ * 7,
                                                 blk_dw_b + i * H_, blk_ln_g + i * H_,
                                                 blk_ln_b + i * H_);
        // GEMM1: 128x192 tiles; 128m x 8n = 1024 blocks
        k_g192p<1, 8><<<1024, 512, 0, stream>>>(
            tmph, tmpl, w1h + (long)i * 589824, w1l + (long)i * 589824,
            blk_b1 + i * H4_, nullptr, nullptr, ht4h, ht4l, H4_, H_);
        // GEMM2: 128x192 tiles; 128m x 2n = 256 blocks = 1 exact round
        k_g192p<2, 2><<<256, 512, 0, stream>>>(
            ht4h, ht4l, w2h + (long)i * 589824, w2l + (long)i * 589824,
            blk_b2 + i * H_, h, h, nullptr, nullptr, H_, H4_);
    }

    k_outconv_argmin<<<BT_ / 16, 256, 0, stream>>>(h, out_w, out_b, emb, out);
}